// Round 6
// baseline (1425.071 us; speedup 1.0000x reference)
//
#include <hip/hip_runtime.h>
#include <hip/hip_bf16.h>
#include <stdint.h>

#define S_ 64
#define B_ 64
#define E_ 512
#define H_ 512
#define V_ 32000
#define G4 2048   // 4*H
#define SB 4096   // S*B
#define NG 4096   // G0 row width: 2 dirs * 4H

typedef __attribute__((ext_vector_type(8))) short short8;
typedef __attribute__((ext_vector_type(4))) float f32x4;
typedef __attribute__((ext_vector_type(4))) int i32x4;

static __device__ __forceinline__ unsigned short f2bf(float f) {
  unsigned u = __float_as_uint(f);
  u += 0x7fff + ((u >> 16) & 1);   // RNE
  return (unsigned short)(u >> 16);
}
static __device__ __forceinline__ float sigm(float x) {
  return 1.f / (1.f + expf(-x));
}

__device__ __forceinline__ void gload_lds16(const void* g, void* l) {
  __builtin_amdgcn_global_load_lds(
      (const __attribute__((address_space(1))) void*)g,
      (__attribute__((address_space(3))) void*)l, 16, 0, 0);
}

// coherent (device-visible) 16-byte store: writes through past the XCD L2
__device__ __forceinline__ void st128_sys(void* p, i32x4 v) {
  asm volatile("global_store_dwordx4 %0, %1, off sc0 sc1"
               :: "v"((unsigned long long)p), "v"(v) : "memory");
}
__device__ __forceinline__ void wait_vm0() {
  asm volatile("s_waitcnt vmcnt(0)" ::: "memory");
}

// relaxed spin until *c >= tgt (agent-scope atomic load bypasses XCD L2)
__device__ __forceinline__ void spin_ge(unsigned* c, unsigned tgt) {
  while (__hip_atomic_load(c, __ATOMIC_RELAXED, __HIP_MEMORY_SCOPE_AGENT) < tgt)
    __builtin_amdgcn_s_sleep(4);
}
__device__ __forceinline__ void arrive(unsigned* c) {
  __hip_atomic_fetch_add(c, 1u, __ATOMIC_RELAXED, __HIP_MEMORY_SCOPE_AGENT);
}

// counter slot index: per (step, dir, part), 256B apart
#define CIDX(t, d, p) ((((t) * 8) + ((d) * 4) + (p)) * 64)
#define CNT_BYTES (64 * 8 * 64 * 4)

__global__ void k_f2bf(const float* __restrict__ in, unsigned short* __restrict__ out, int n) {
  int i = blockIdx.x * blockDim.x + threadIdx.x;
  int stride = gridDim.x * blockDim.x;
  for (; i < n; i += stride) out[i] = f2bf(in[i]);
}

__global__ void k_addbias(const float* __restrict__ a, const float* __restrict__ b,
                          float* __restrict__ out, int n) {
  int i = blockIdx.x * blockDim.x + threadIdx.x;
  if (i < n) out[i] = a[i] + b[i];
}

__global__ void k_gather(const int* __restrict__ Y, const float* __restrict__ emb,
                         unsigned short* __restrict__ X) {
  int sb = blockIdx.x;
  int t = sb >> 6, b = sb & 63;
  int idx = (t == 0) ? Y[b * S_ + 1] : Y[b * S_ + t - 1];
  const float* src = emb + (size_t)idx * E_;
  unsigned short* dst = X + (size_t)sb * E_;
  for (int e = threadIdx.x; e < E_; e += blockDim.x) dst[e] = f2bf(src[e]);
}

__global__ void k_init_h(const float* __restrict__ hid,
                         unsigned short* __restrict__ h0i, unsigned short* __restrict__ h1i) {
  int i = blockIdx.x * blockDim.x + threadIdx.x;
  if (i >= 4 * B_ * H_) return;
  unsigned short v = f2bf(hid[i]);
  if (i < 2 * B_ * H_) h0i[i] = v;
  else h1i[i - 2 * B_ * H_] = v;
}

// ---------------- GEMM: C[M,N] = A[M,K] @ B[N,K]^T + bias (m97-style) ----------------
template <bool PERMUTE, bool NT>
__global__ __launch_bounds__(256) void k_gemm_nt(
    const unsigned short* __restrict__ A, const unsigned short* __restrict__ B,
    const float* __restrict__ bias, float* __restrict__ C,
    int M, int N, int K, int nTN) {
  __shared__ unsigned short Als[128 * 32];
  __shared__ unsigned short Bls[128 * 32];
  int tid = threadIdx.x;
  int bm = blockIdx.x / nTN, bn = blockIdx.x - bm * nTN;
  int w = tid >> 6, l = tid & 63;
  int wr = w >> 1, wc = w & 1;
  int lr = l & 15, hi = l >> 4;
  int c0 = w * 128 + l;
  int row0 = c0 >> 2, ks0 = (((c0 & 3) ^ (row0 & 3)) * 8);
  int c1 = c0 + 64;
  int row1 = c1 >> 2, ks1 = (((c1 & 3) ^ (row1 & 3)) * 8);
  const unsigned short* Ab = A + (size_t)(bm * 128) * K;
  const unsigned short* Bb = B + (size_t)(bn * 128) * K;
  unsigned short* AlsW = &Als[w * 1024];
  unsigned short* BlsW = &Bls[w * 1024];
  int co = ((hi ^ (lr & 3)) * 8);
  f32x4 acc[4][4] = {};
  for (int kk = 0; kk < K; kk += 32) {
    __syncthreads();
    gload_lds16(Ab + (size_t)row0 * K + kk + ks0, AlsW);
    gload_lds16(Ab + (size_t)row1 * K + kk + ks1, AlsW + 512);
    gload_lds16(Bb + (size_t)row0 * K + kk + ks0, BlsW);
    gload_lds16(Bb + (size_t)row1 * K + kk + ks1, BlsW + 512);
    __syncthreads();
    short8 af[4], bfr[4];
#pragma unroll
    for (int r = 0; r < 4; r++)
      af[r] = *(const short8*)&Als[(wr * 64 + r * 16 + lr) * 32 + co];
#pragma unroll
    for (int c4 = 0; c4 < 4; c4++)
      bfr[c4] = *(const short8*)&Bls[(wc * 64 + c4 * 16 + lr) * 32 + co];
#pragma unroll
    for (int r = 0; r < 4; r++)
#pragma unroll
      for (int c4 = 0; c4 < 4; c4++)
        acc[r][c4] = __builtin_amdgcn_mfma_f32_16x16x32_bf16(af[r], bfr[c4], acc[r][c4], 0, 0, 0);
  }
  int rbase = bm * 128 + wr * 64 + hi * 4;
  int cbase = bn * 128 + wc * 64 + lr;
#pragma unroll
  for (int r = 0; r < 4; r++) {
#pragma unroll
    for (int c4 = 0; c4 < 4; c4++) {
      int cc = cbase + c4 * 16;
      float bv = bias[cc];
#pragma unroll
      for (int j = 0; j < 4; j++) {
        int rr = rbase + r * 16 + j;
        size_t orow = PERMUTE ? (size_t)((rr & 63) * 64 + (rr >> 6)) : (size_t)rr;
        float v = acc[r][c4][j] + bv;
        float* p = &C[orow * (size_t)N + cc];
        if (NT) __builtin_nontemporal_store(v, p);
        else *p = v;
      }
    }
  }
}

// ---------------- fused persistent 2-layer bidirectional LSTM (self-timed) ----------------
// 192 blocks: [0,64): layer 0 (d=blk>>5, jt=blk&31); [64,192): layer 1
// (idx=blk-64, d=idx>>6, jt8=idx&63). Producer/consumer flags, no lockstep:
//   cnt0[t][d][p] (tgt 8): H0[t] dir-d part-p published     (p = jt&3)
//   cnt1[t][d][p] (tgt 16): O1[t] dir-d part-p published    (p = jt8&3)
// publish: LDS-stage the h tile, coalesced global_store_dwordx4 sc0sc1,
// vmcnt(0), barrier, relaxed flag add. consumer: relaxed spin + one
// agent-acquire fence per step, then plain cached loads.
#define LDW0 520    // l0: 64 rows x (512+8)
#define LDW1 1544   // l1: 32 rows x (1536+8)
#define NBLK 192

__global__ __launch_bounds__(256) void k_fused_lstm(
    const unsigned short* __restrict__ h0i,   // (2,B,H) bf16
    const unsigned short* __restrict__ h1i,   // (2,B,H) bf16
    const float* __restrict__ cell,           // (4,B,H) fp32 [l0f,l0b,l1f,l1b]
    const unsigned short* __restrict__ whh0,  // (2,2048,512) bf16
    const unsigned short* __restrict__ wih1,  // (2,2048,1024) bf16
    const unsigned short* __restrict__ whh1,  // (2,2048,512) bf16
    const float* __restrict__ b1s,            // (2,2048) fp32
    const float* __restrict__ G0,             // (SB,NG) fp32
    unsigned short* __restrict__ H0,          // (SB,1024) bf16  layer-0 output
    unsigned short* __restrict__ O1,          // (SB,1024) bf16  layer-1 output
    unsigned* __restrict__ cnt0, unsigned* __restrict__ cnt1) {
  __shared__ unsigned short SM[32 * LDW1];    // 98,816 B (l0 uses 66,560 of it)
  __shared__ __align__(16) unsigned short HS[64 * 16];  // publish staging
  int tid = threadIdx.x;
  int w = tid >> 6, l = tid & 63;
  int lr = l & 15, hi = l >> 4;

  if (blockIdx.x < 64) {
    // ================= LAYER 0 =================
    int d = blockIdx.x >> 5, jt = blockIdx.x & 31;
    const unsigned short* Wd = whh0 + (size_t)d * (G4 * H_);
    for (int c = tid; c < 64 * 64; c += 256) {
      int row = c >> 6, ck = c & 63;
      int g = row >> 4, r16 = row & 15;
      *(int4*)&SM[row * LDW0 + ck * 8] =
          *(const int4*)&Wd[(size_t)(g * H_ + jt * 16 + r16) * H_ + ck * 8];
    }
    int j = jt * 16 + lr;
    int b0 = w * 16 + hi * 4;
    f32x4 creg;
    {
      const float* cd = cell + (size_t)d * (B_ * H_);
#pragma unroll
      for (int jj = 0; jj < 4; jj++) creg[jj] = cd[(size_t)(b0 + jj) * H_ + j];
    }
    __syncthreads();
    const float* G_dj = G0 + d * G4;
    float gv[4][4];
    auto preloadG = [&](int t) {
#pragma unroll
      for (int jj = 0; jj < 4; jj++) {
        const float* Gb = G_dj + (size_t)(t * B_ + b0 + jj) * NG;
#pragma unroll
        for (int g = 0; g < 4; g++) gv[g][jj] = Gb[g * 512 + j];
      }
    };
    preloadG(0);
    for (int t = 0; t < S_; ++t) {
      if (t >= 1) {
        if (tid < 4) spin_ge(&cnt0[CIDX(t - 1, d, tid)], 8);
        __builtin_amdgcn_fence(__ATOMIC_ACQUIRE, "agent");
        __syncthreads();
      }
      const unsigned short* hp = (t == 0) ? h0i + (size_t)d * (B_ * H_)
                                          : H0 + (size_t)(t - 1) * B_ * 1024 + d * 512;
      size_t hstr = (t == 0) ? (size_t)H_ : 1024;
      const unsigned short* arow = hp + (size_t)(w * 16 + lr) * hstr + hi * 8;
      f32x4 acc[4] = {};
#pragma unroll
      for (int ki = 0; ki < 16; ki++) {
        short8 a = *(const short8*)&arow[ki * 32];
#pragma unroll
        for (int g = 0; g < 4; g++) {
          short8 bfr = *(const short8*)&SM[(g * 16 + lr) * LDW0 + ki * 32 + hi * 8];
          acc[g] = __builtin_amdgcn_mfma_f32_16x16x32_bf16(a, bfr, acc[g], 0, 0, 0);
        }
      }
#pragma unroll
      for (int jj = 0; jj < 4; jj++) {
        float gi = acc[0][jj] + gv[0][jj];
        float gf = acc[1][jj] + gv[1][jj];
        float gg = acc[2][jj] + gv[2][jj];
        float go = acc[3][jj] + gv[3][jj];
        float c = sigm(gf) * creg[jj] + sigm(gi) * tanhf(gg);
        creg[jj] = c;
        HS[(b0 + jj) * 16 + lr] = f2bf(sigm(go) * tanhf(c));
      }
      __syncthreads();
      unsigned short* Ho = H0 + (size_t)t * B_ * 1024 + d * 512 + jt * 16;
      if (tid < 128) {
        int r = tid >> 1, half = tid & 1;
        i32x4 v = *(const i32x4*)&HS[r * 16 + half * 8];
        st128_sys(&Ho[(size_t)r * 1024 + half * 8], v);
      }
      wait_vm0();
      __syncthreads();
      if (tid == 0) arrive(&cnt0[CIDX(t, d, jt & 3)]);
      if (t + 1 < S_) preloadG(t + 1);
    }
  } else {
    // ================= LAYER 1 =================
    int idx = blockIdx.x - 64;
    int d = idx >> 6, jt8 = idx & 63;
    int j0 = jt8 * 8;
    {
      const unsigned short* Wih = wih1 + (size_t)d * (G4 * 1024);
      const unsigned short* Whh = whh1 + (size_t)d * (G4 * H_);
      for (int c = tid; c < 32 * 192; c += 256) {
        int r = c / 192, ck = c - r * 192;
        int g = r >> 3, jc = r & 7;
        const unsigned short* src =
            (ck < 128) ? Wih + (size_t)(g * H_ + j0 + jc) * 1024 + ck * 8
                       : Whh + (size_t)(g * H_ + j0 + jc) * H_ + (ck - 128) * 8;
        *(int4*)&SM[r * LDW1 + ck * 8] = *(const int4*)src;
      }
    }
    int j = j0 + (lr & 7);
    const float* b1d = b1s + d * G4;
    float bi_ = b1d[j], bf_ = b1d[512 + j], bg_ = b1d[1024 + j], bo_ = b1d[1536 + j];
    int b0 = w * 16 + hi * 4;
    f32x4 creg = {};
    if (lr < 8) {
      const float* cd = cell + (size_t)(2 + d) * (B_ * H_);
#pragma unroll
      for (int jj = 0; jj < 4; jj++) creg[jj] = cd[(size_t)(b0 + jj) * H_ + j];
    }
    __syncthreads();
    for (int t = 0; t < S_; ++t) {
      // wait: H0[t] (both dirs) and O1[t-1] (own dir)
      if (tid < 8) spin_ge(&cnt0[CIDX(t, 0, 0) + tid * 64], 8);
      if (t >= 1 && tid >= 8 && tid < 12) spin_ge(&cnt1[CIDX(t - 1, d, tid - 8)], 16);
      __builtin_amdgcn_fence(__ATOMIC_ACQUIRE, "agent");
      __syncthreads();
      const unsigned short* x1row = H0 + ((size_t)t * B_ + w * 16 + lr) * 1024 + hi * 8;
      const unsigned short* hprev = (t == 0)
          ? h1i + (size_t)d * (B_ * H_) + (size_t)(w * 16 + lr) * H_ + hi * 8
          : O1 + ((size_t)(t - 1) * B_ + w * 16 + lr) * 1024 + d * 512 + hi * 8;
      f32x4 acc0 = {}, acc1 = {};
#pragma unroll 8
      for (int ki = 0; ki < 32; ki++) {
        short8 a = *(const short8*)&x1row[ki * 32];
        short8 bA = *(const short8*)&SM[(size_t)lr * LDW1 + ki * 32 + hi * 8];
        short8 bB = *(const short8*)&SM[(size_t)(16 + lr) * LDW1 + ki * 32 + hi * 8];
        acc0 = __builtin_amdgcn_mfma_f32_16x16x32_bf16(a, bA, acc0, 0, 0, 0);
        acc1 = __builtin_amdgcn_mfma_f32_16x16x32_bf16(a, bB, acc1, 0, 0, 0);
      }
#pragma unroll 8
      for (int ki = 0; ki < 16; ki++) {
        short8 a = *(const short8*)&hprev[ki * 32];
        short8 bA = *(const short8*)&SM[(size_t)lr * LDW1 + 1024 + ki * 32 + hi * 8];
        short8 bB = *(const short8*)&SM[(size_t)(16 + lr) * LDW1 + 1024 + ki * 32 + hi * 8];
        acc0 = __builtin_amdgcn_mfma_f32_16x16x32_bf16(a, bA, acc0, 0, 0, 0);
        acc1 = __builtin_amdgcn_mfma_f32_16x16x32_bf16(a, bB, acc1, 0, 0, 0);
      }
      float pf[4], po[4];
#pragma unroll
      for (int jj = 0; jj < 4; jj++) {
        pf[jj] = __shfl_xor(acc0[jj], 8);
        po[jj] = __shfl_xor(acc1[jj], 8);
      }
      if (lr < 8) {
#pragma unroll
        for (int jj = 0; jj < 4; jj++) {
          float gi = acc0[jj] + bi_;
          float gf = pf[jj] + bf_;
          float gg = acc1[jj] + bg_;
          float go = po[jj] + bo_;
          float c = sigm(gf) * creg[jj] + sigm(gi) * tanhf(gg);
          creg[jj] = c;
          HS[(b0 + jj) * 8 + lr] = f2bf(sigm(go) * tanhf(c));
        }
      }
      __syncthreads();
      unsigned short* Oo = O1 + (size_t)t * B_ * 1024 + d * 512 + j0;
      if (tid < 64) {
        i32x4 v = *(const i32x4*)&HS[tid * 8];
        st128_sys(&Oo[(size_t)tid * 1024], v);
      }
      wait_vm0();
      __syncthreads();
      if (tid == 0 && t + 1 < S_) arrive(&cnt1[CIDX(t, d, jt8 & 3)]);
    }
  }
}

extern "C" void kernel_launch(void* const* d_in, const int* in_sizes, int n_in,
                              void* d_out, int out_size, void* d_ws, size_t ws_size,
                              hipStream_t stream) {
  const float* hidden = (const float*)d_in[0];
  const float* cell   = (const float*)d_in[1];
  const int*   Y      = (const int*)d_in[2];
  const float* emb    = (const float*)d_in[3];
  const float* wih0   = (const float*)d_in[4];
  const float* whh0   = (const float*)d_in[5];
  const float* bih0   = (const float*)d_in[6];
  const float* bhh0   = (const float*)d_in[7];
  const float* wih1   = (const float*)d_in[8];
  const float* whh1   = (const float*)d_in[9];
  const float* bih1   = (const float*)d_in[10];
  const float* bhh1   = (const float*)d_in[11];
  const float* fcw    = (const float*)d_in[12];
  const float* fcb    = (const float*)d_in[13];

  char* ws = (char*)d_ws;
  size_t off = 0;
  auto alloc = [&](size_t bytes) {
    void* p = ws + off;
    off += (bytes + 255) & ~(size_t)255;
    return p;
  };
  unsigned short* wih0b = (unsigned short*)alloc((size_t)2 * G4 * E_ * 2);
  unsigned short* whh0b = (unsigned short*)alloc((size_t)2 * G4 * H_ * 2);
  unsigned short* wih1b = (unsigned short*)alloc((size_t)2 * G4 * 1024 * 2);
  unsigned short* whh1b = (unsigned short*)alloc((size_t)2 * G4 * H_ * 2);
  unsigned short* fcwb  = (unsigned short*)alloc((size_t)V_ * 1024 * 2);
  unsigned short* Xb    = (unsigned short*)alloc((size_t)SB * E_ * 2);
  unsigned short* H0    = (unsigned short*)alloc((size_t)SB * 1024 * 2);
  unsigned short* O1    = (unsigned short*)alloc((size_t)SB * 1024 * 2);
  unsigned short* h0i   = (unsigned short*)alloc((size_t)2 * B_ * H_ * 2);
  unsigned short* h1i   = (unsigned short*)alloc((size_t)2 * B_ * H_ * 2);
  float* b0s = (float*)alloc((size_t)2 * G4 * 4);
  float* b1s = (float*)alloc((size_t)2 * G4 * 4);
  unsigned* cnt0 = (unsigned*)alloc(CNT_BYTES);
  unsigned* cnt1 = (unsigned*)alloc(CNT_BYTES);
  (void)ws_size;

  // G0 lives in d_out (fully consumed before final GEMM overwrites it).
  float* G0 = (float*)d_out;   // (SB, NG) = 64 MB

  // --- prep ---
  k_f2bf<<<2048, 256, 0, stream>>>(wih0, wih0b, 2 * G4 * E_);
  k_f2bf<<<2048, 256, 0, stream>>>(whh0, whh0b, 2 * G4 * H_);
  k_f2bf<<<2048, 256, 0, stream>>>(wih1, wih1b, 2 * G4 * 1024);
  k_f2bf<<<2048, 256, 0, stream>>>(whh1, whh1b, 2 * G4 * H_);
  k_f2bf<<<4096, 256, 0, stream>>>(fcw, fcwb, V_ * 1024);
  k_addbias<<<16, 256, 0, stream>>>(bih0, bhh0, b0s, 2 * G4);
  k_addbias<<<16, 256, 0, stream>>>(bih1, bhh1, b1s, 2 * G4);
  k_gather<<<SB, 256, 0, stream>>>(Y, emb, Xb);
  k_init_h<<<512, 256, 0, stream>>>(hidden, h0i, h1i);
  (void)hipMemsetAsync(cnt0, 0, CNT_BYTES, stream);
  (void)hipMemsetAsync(cnt1, 0, CNT_BYTES, stream);

  // --- layer-0 input gates: G0 = X @ [wih0 both dirs]^T + b0 ---
  k_gemm_nt<false, false><<<(SB / 128) * (NG / 128), 256, 0, stream>>>(
      Xb, wih0b, b0s, G0, SB, NG, E_, NG / 128);

  // --- fused persistent recurrence (self-timed chains) ---
  k_fused_lstm<<<NBLK, 256, 0, stream>>>(h0i, h1i, cell, whh0b, wih1b, whh1b,
                                         b1s, G0, H0, O1, cnt0, cnt1);

  // --- final projection: out[b*64+t, v] = O1[t*64+b,:] @ fcw[v,:]^T + fcb[v] ---
  k_gemm_nt<true, true><<<(SB / 128) * (V_ / 128), 256, 0, stream>>>(
      O1, fcwb, fcb, (float*)d_out, SB, V_, 1024, V_ / 128);
}

// Round 7
// 1234.635 us; speedup vs baseline: 1.1542x; 1.1542x over previous
//
#include <hip/hip_runtime.h>
#include <hip/hip_bf16.h>
#include <stdint.h>

#define S_ 64
#define B_ 64
#define E_ 512
#define H_ 512
#define V_ 32000
#define G4 2048   // 4*H
#define SB 4096   // S*B
#define NG 4096   // G0 row width: 2 dirs * 4H

typedef __attribute__((ext_vector_type(8))) short short8;
typedef __attribute__((ext_vector_type(4))) float f32x4;
typedef __attribute__((ext_vector_type(4))) int i32x4;

static __device__ __forceinline__ unsigned short f2bf(float f) {
  unsigned u = __float_as_uint(f);
  u += 0x7fff + ((u >> 16) & 1);   // RNE
  return (unsigned short)(u >> 16);
}
static __device__ __forceinline__ float sigm(float x) {
  return 1.f / (1.f + expf(-x));
}

__device__ __forceinline__ void gload_lds16(const void* g, void* l) {
  __builtin_amdgcn_global_load_lds(
      (const __attribute__((address_space(1))) void*)g,
      (__attribute__((address_space(3))) void*)l, 16, 0, 0);
}

// coherent (device-visible) 16-byte store: write-through past the XCD L2
__device__ __forceinline__ void st128_sys(void* p, i32x4 v) {
  asm volatile("global_store_dwordx4 %0, %1, off sc0 sc1"
               :: "v"((unsigned long long)p), "v"(v) : "memory");
}
__device__ __forceinline__ void wait_vm0() {
  asm volatile("s_waitcnt vmcnt(0)" ::: "memory");
}

// relaxed spin until *c >= tgt (agent-scope atomic load bypasses XCD L2)
__device__ __forceinline__ void spin_ge(unsigned* c, unsigned tgt) {
  while (__hip_atomic_load(c, __ATOMIC_RELAXED, __HIP_MEMORY_SCOPE_AGENT) < tgt)
    __builtin_amdgcn_s_sleep(1);
}
__device__ __forceinline__ void arrive(unsigned* c) {
  __hip_atomic_fetch_add(c, 1u, __ATOMIC_RELAXED, __HIP_MEMORY_SCOPE_AGENT);
}

// counter slot index: per (step, dir, part), 256B apart
#define CIDX(t, d, p) ((((t) * 8) + ((d) * 4) + (p)) * 64)
#define CNT_BYTES (64 * 8 * 64 * 4)

__global__ void k_f2bf(const float* __restrict__ in, unsigned short* __restrict__ out, int n) {
  int i = blockIdx.x * blockDim.x + threadIdx.x;
  int stride = gridDim.x * blockDim.x;
  for (; i < n; i += stride) out[i] = f2bf(in[i]);
}

__global__ void k_addbias(const float* __restrict__ a, const float* __restrict__ b,
                          float* __restrict__ out, int n) {
  int i = blockIdx.x * blockDim.x + threadIdx.x;
  if (i < n) out[i] = a[i] + b[i];
}

__global__ void k_gather(const int* __restrict__ Y, const float* __restrict__ emb,
                         unsigned short* __restrict__ X) {
  int sb = blockIdx.x;
  int t = sb >> 6, b = sb & 63;
  int idx = (t == 0) ? Y[b * S_ + 1] : Y[b * S_ + t - 1];
  const float* src = emb + (size_t)idx * E_;
  unsigned short* dst = X + (size_t)sb * E_;
  for (int e = threadIdx.x; e < E_; e += blockDim.x) dst[e] = f2bf(src[e]);
}

__global__ void k_init_h(const float* __restrict__ hid,
                         unsigned short* __restrict__ h0i, unsigned short* __restrict__ h1i) {
  int i = blockIdx.x * blockDim.x + threadIdx.x;
  if (i >= 4 * B_ * H_) return;
  unsigned short v = f2bf(hid[i]);
  if (i < 2 * B_ * H_) h0i[i] = v;
  else h1i[i - 2 * B_ * H_] = v;
}

// ---------------- GEMM: C[M,N] = A[M,K] @ B[N,K]^T + bias (m97-style) ----------------
template <bool PERMUTE, bool NT>
__global__ __launch_bounds__(256) void k_gemm_nt(
    const unsigned short* __restrict__ A, const unsigned short* __restrict__ B,
    const float* __restrict__ bias, float* __restrict__ C,
    int M, int N, int K, int nTN) {
  __shared__ unsigned short Als[128 * 32];
  __shared__ unsigned short Bls[128 * 32];
  int tid = threadIdx.x;
  int bm = blockIdx.x / nTN, bn = blockIdx.x - bm * nTN;
  int w = tid >> 6, l = tid & 63;
  int wr = w >> 1, wc = w & 1;
  int lr = l & 15, hi = l >> 4;
  int c0 = w * 128 + l;
  int row0 = c0 >> 2, ks0 = (((c0 & 3) ^ (row0 & 3)) * 8);
  int c1 = c0 + 64;
  int row1 = c1 >> 2, ks1 = (((c1 & 3) ^ (row1 & 3)) * 8);
  const unsigned short* Ab = A + (size_t)(bm * 128) * K;
  const unsigned short* Bb = B + (size_t)(bn * 128) * K;
  unsigned short* AlsW = &Als[w * 1024];
  unsigned short* BlsW = &Bls[w * 1024];
  int co = ((hi ^ (lr & 3)) * 8);
  f32x4 acc[4][4] = {};
  for (int kk = 0; kk < K; kk += 32) {
    __syncthreads();
    gload_lds16(Ab + (size_t)row0 * K + kk + ks0, AlsW);
    gload_lds16(Ab + (size_t)row1 * K + kk + ks1, AlsW + 512);
    gload_lds16(Bb + (size_t)row0 * K + kk + ks0, BlsW);
    gload_lds16(Bb + (size_t)row1 * K + kk + ks1, BlsW + 512);
    __syncthreads();
    short8 af[4], bfr[4];
#pragma unroll
    for (int r = 0; r < 4; r++)
      af[r] = *(const short8*)&Als[(wr * 64 + r * 16 + lr) * 32 + co];
#pragma unroll
    for (int c4 = 0; c4 < 4; c4++)
      bfr[c4] = *(const short8*)&Bls[(wc * 64 + c4 * 16 + lr) * 32 + co];
#pragma unroll
    for (int r = 0; r < 4; r++)
#pragma unroll
      for (int c4 = 0; c4 < 4; c4++)
        acc[r][c4] = __builtin_amdgcn_mfma_f32_16x16x32_bf16(af[r], bfr[c4], acc[r][c4], 0, 0, 0);
  }
  int rbase = bm * 128 + wr * 64 + hi * 4;
  int cbase = bn * 128 + wc * 64 + lr;
#pragma unroll
  for (int r = 0; r < 4; r++) {
#pragma unroll
    for (int c4 = 0; c4 < 4; c4++) {
      int cc = cbase + c4 * 16;
      float bv = bias[cc];
#pragma unroll
      for (int j = 0; j < 4; j++) {
        int rr = rbase + r * 16 + j;
        size_t orow = PERMUTE ? (size_t)((rr & 63) * 64 + (rr >> 6)) : (size_t)rr;
        float v = acc[r][c4][j] + bv;
        float* p = &C[orow * (size_t)N + cc];
        if (NT) __builtin_nontemporal_store(v, p);
        else *p = v;
      }
    }
  }
}

// ---------------- fused persistent 2-layer bidirectional LSTM (self-timed) ----------------
// 192 blocks: [0,64): layer 0 (d=blk>>5, jt=blk&31); [64,192): layer 1
// (idx=blk-64, d=idx>>6, jt8=idx&63). Producer/consumer flags, no lockstep:
//   cnt0[t][d][p] (tgt 8): H0[t] dir-d part-p published     (p = jt&3)
//   cnt1[t][d][p] (tgt 16): O1[t] dir-d part-p published    (p = jt8&3)
// publish: LDS-stage tile -> coalesced global_store_dwordx4 sc0sc1 (write-through
// to coherence point) -> vmcnt(0) -> barrier -> relaxed flag add.
// consume: relaxed agent-scope spin -> barrier -> PLAIN cached loads.
// NO acquire fence / L2 invalidate: every published tile occupies fresh
// cachelines (written once, read only after the flag), so no consumer L2 can
// hold a stale copy; kernel-boundary flushes cover pre-kernel writes.
#define LDW0 520    // l0: 64 rows x (512+8)
#define LDW1 1544   // l1: 32 rows x (1536+8)
#define NBLK 192

__global__ __launch_bounds__(256) void k_fused_lstm(
    const unsigned short* __restrict__ h0i,   // (2,B,H) bf16
    const unsigned short* __restrict__ h1i,   // (2,B,H) bf16
    const float* __restrict__ cell,           // (4,B,H) fp32 [l0f,l0b,l1f,l1b]
    const unsigned short* __restrict__ whh0,  // (2,2048,512) bf16
    const unsigned short* __restrict__ wih1,  // (2,2048,1024) bf16
    const unsigned short* __restrict__ whh1,  // (2,2048,512) bf16
    const float* __restrict__ b1s,            // (2,2048) fp32
    const float* __restrict__ G0,             // (SB,NG) fp32
    unsigned short* __restrict__ H0,          // (SB,1024) bf16  layer-0 output
    unsigned short* __restrict__ O1,          // (SB,1024) bf16  layer-1 output
    unsigned* __restrict__ cnt0, unsigned* __restrict__ cnt1) {
  __shared__ unsigned short SM[32 * LDW1];    // 98,816 B (l0 uses 66,560 of it)
  __shared__ __align__(16) unsigned short HS[64 * 16];  // publish staging
  int tid = threadIdx.x;
  int w = tid >> 6, l = tid & 63;
  int lr = l & 15, hi = l >> 4;

  if (blockIdx.x < 64) {
    // ================= LAYER 0 =================
    int d = blockIdx.x >> 5, jt = blockIdx.x & 31;
    const unsigned short* Wd = whh0 + (size_t)d * (G4 * H_);
    for (int c = tid; c < 64 * 64; c += 256) {
      int row = c >> 6, ck = c & 63;
      int g = row >> 4, r16 = row & 15;
      *(int4*)&SM[row * LDW0 + ck * 8] =
          *(const int4*)&Wd[(size_t)(g * H_ + jt * 16 + r16) * H_ + ck * 8];
    }
    int j = jt * 16 + lr;
    int b0 = w * 16 + hi * 4;
    f32x4 creg;
    {
      const float* cd = cell + (size_t)d * (B_ * H_);
#pragma unroll
      for (int jj = 0; jj < 4; jj++) creg[jj] = cd[(size_t)(b0 + jj) * H_ + j];
    }
    __syncthreads();
    const float* G_dj = G0 + d * G4;
    float gv[4][4];
    auto preloadG = [&](int t) {
#pragma unroll
      for (int jj = 0; jj < 4; jj++) {
        const float* Gb = G_dj + (size_t)(t * B_ + b0 + jj) * NG;
#pragma unroll
        for (int g = 0; g < 4; g++) gv[g][jj] = Gb[g * 512 + j];
      }
    };
    preloadG(0);
    for (int t = 0; t < S_; ++t) {
      if (t >= 1) {
        if (tid < 4) spin_ge(&cnt0[CIDX(t - 1, d, tid)], 8);
        __syncthreads();
      }
      const unsigned short* hp = (t == 0) ? h0i + (size_t)d * (B_ * H_)
                                          : H0 + (size_t)(t - 1) * B_ * 1024 + d * 512;
      size_t hstr = (t == 0) ? (size_t)H_ : 1024;
      const unsigned short* arow = hp + (size_t)(w * 16 + lr) * hstr + hi * 8;
      f32x4 acc[4] = {};
#pragma unroll
      for (int ki = 0; ki < 16; ki++) {
        short8 a = *(const short8*)&arow[ki * 32];
#pragma unroll
        for (int g = 0; g < 4; g++) {
          short8 bfr = *(const short8*)&SM[(g * 16 + lr) * LDW0 + ki * 32 + hi * 8];
          acc[g] = __builtin_amdgcn_mfma_f32_16x16x32_bf16(a, bfr, acc[g], 0, 0, 0);
        }
      }
#pragma unroll
      for (int jj = 0; jj < 4; jj++) {
        float gi = acc[0][jj] + gv[0][jj];
        float gf = acc[1][jj] + gv[1][jj];
        float gg = acc[2][jj] + gv[2][jj];
        float go = acc[3][jj] + gv[3][jj];
        float c = sigm(gf) * creg[jj] + sigm(gi) * tanhf(gg);
        creg[jj] = c;
        HS[(b0 + jj) * 16 + lr] = f2bf(sigm(go) * tanhf(c));
      }
      __syncthreads();
      unsigned short* Ho = H0 + (size_t)t * B_ * 1024 + d * 512 + jt * 16;
      if (tid < 128) {
        int r = tid >> 1, half = tid & 1;
        i32x4 v = *(const i32x4*)&HS[r * 16 + half * 8];
        st128_sys(&Ho[(size_t)r * 1024 + half * 8], v);
      }
      wait_vm0();
      __syncthreads();
      if (tid == 0) arrive(&cnt0[CIDX(t, d, jt & 3)]);
      if (t + 1 < S_) preloadG(t + 1);
    }
  } else {
    // ================= LAYER 1 =================
    int idx = blockIdx.x - 64;
    int d = idx >> 6, jt8 = idx & 63;
    int j0 = jt8 * 8;
    {
      const unsigned short* Wih = wih1 + (size_t)d * (G4 * 1024);
      const unsigned short* Whh = whh1 + (size_t)d * (G4 * H_);
      for (int c = tid; c < 32 * 192; c += 256) {
        int r = c / 192, ck = c - r * 192;
        int g = r >> 3, jc = r & 7;
        const unsigned short* src =
            (ck < 128) ? Wih + (size_t)(g * H_ + j0 + jc) * 1024 + ck * 8
                       : Whh + (size_t)(g * H_ + j0 + jc) * H_ + (ck - 128) * 8;
        *(int4*)&SM[r * LDW1 + ck * 8] = *(const int4*)src;
      }
    }
    int j = j0 + (lr & 7);
    const float* b1d = b1s + d * G4;
    float bi_ = b1d[j], bf_ = b1d[512 + j], bg_ = b1d[1024 + j], bo_ = b1d[1536 + j];
    int b0 = w * 16 + hi * 4;
    f32x4 creg = {};
    if (lr < 8) {
      const float* cd = cell + (size_t)(2 + d) * (B_ * H_);
#pragma unroll
      for (int jj = 0; jj < 4; jj++) creg[jj] = cd[(size_t)(b0 + jj) * H_ + j];
    }
    __syncthreads();
    for (int t = 0; t < S_; ++t) {
      // wait: H0[t] (both dirs) and O1[t-1] (own dir)
      if (tid < 8) spin_ge(&cnt0[CIDX(t, 0, 0) + tid * 64], 8);
      if (t >= 1 && tid >= 8 && tid < 12) spin_ge(&cnt1[CIDX(t - 1, d, tid - 8)], 16);
      __syncthreads();
      const unsigned short* x1row = H0 + ((size_t)t * B_ + w * 16 + lr) * 1024 + hi * 8;
      const unsigned short* hprev = (t == 0)
          ? h1i + (size_t)d * (B_ * H_) + (size_t)(w * 16 + lr) * H_ + hi * 8
          : O1 + ((size_t)(t - 1) * B_ + w * 16 + lr) * 1024 + d * 512 + hi * 8;
      f32x4 acc0 = {}, acc1 = {};
#pragma unroll 8
      for (int ki = 0; ki < 32; ki++) {
        short8 a = *(const short8*)&x1row[ki * 32];
        short8 bA = *(const short8*)&SM[(size_t)lr * LDW1 + ki * 32 + hi * 8];
        short8 bB = *(const short8*)&SM[(size_t)(16 + lr) * LDW1 + ki * 32 + hi * 8];
        acc0 = __builtin_amdgcn_mfma_f32_16x16x32_bf16(a, bA, acc0, 0, 0, 0);
        acc1 = __builtin_amdgcn_mfma_f32_16x16x32_bf16(a, bB, acc1, 0, 0, 0);
      }
#pragma unroll 8
      for (int ki = 0; ki < 16; ki++) {
        short8 a = *(const short8*)&hprev[ki * 32];
        short8 bA = *(const short8*)&SM[(size_t)lr * LDW1 + 1024 + ki * 32 + hi * 8];
        short8 bB = *(const short8*)&SM[(size_t)(16 + lr) * LDW1 + 1024 + ki * 32 + hi * 8];
        acc0 = __builtin_amdgcn_mfma_f32_16x16x32_bf16(a, bA, acc0, 0, 0, 0);
        acc1 = __builtin_amdgcn_mfma_f32_16x16x32_bf16(a, bB, acc1, 0, 0, 0);
      }
      float pf[4], po[4];
#pragma unroll
      for (int jj = 0; jj < 4; jj++) {
        pf[jj] = __shfl_xor(acc0[jj], 8);
        po[jj] = __shfl_xor(acc1[jj], 8);
      }
      if (lr < 8) {
#pragma unroll
        for (int jj = 0; jj < 4; jj++) {
          float gi = acc0[jj] + bi_;
          float gf = pf[jj] + bf_;
          float gg = acc1[jj] + bg_;
          float go = po[jj] + bo_;
          float c = sigm(gf) * creg[jj] + sigm(gi) * tanhf(gg);
          creg[jj] = c;
          HS[(b0 + jj) * 8 + lr] = f2bf(sigm(go) * tanhf(c));
        }
      }
      __syncthreads();
      unsigned short* Oo = O1 + (size_t)t * B_ * 1024 + d * 512 + j0;
      if (tid < 64) {
        i32x4 v = *(const i32x4*)&HS[tid * 8];
        st128_sys(&Oo[(size_t)tid * 1024], v);
      }
      wait_vm0();
      __syncthreads();
      if (tid == 0 && t + 1 < S_) arrive(&cnt1[CIDX(t, d, jt8 & 3)]);
    }
  }
}

extern "C" void kernel_launch(void* const* d_in, const int* in_sizes, int n_in,
                              void* d_out, int out_size, void* d_ws, size_t ws_size,
                              hipStream_t stream) {
  const float* hidden = (const float*)d_in[0];
  const float* cell   = (const float*)d_in[1];
  const int*   Y      = (const int*)d_in[2];
  const float* emb    = (const float*)d_in[3];
  const float* wih0   = (const float*)d_in[4];
  const float* whh0   = (const float*)d_in[5];
  const float* bih0   = (const float*)d_in[6];
  const float* bhh0   = (const float*)d_in[7];
  const float* wih1   = (const float*)d_in[8];
  const float* whh1   = (const float*)d_in[9];
  const float* bih1   = (const float*)d_in[10];
  const float* bhh1   = (const float*)d_in[11];
  const float* fcw    = (const float*)d_in[12];
  const float* fcb    = (const float*)d_in[13];

  char* ws = (char*)d_ws;
  size_t off = 0;
  auto alloc = [&](size_t bytes) {
    void* p = ws + off;
    off += (bytes + 255) & ~(size_t)255;
    return p;
  };
  unsigned short* wih0b = (unsigned short*)alloc((size_t)2 * G4 * E_ * 2);
  unsigned short* whh0b = (unsigned short*)alloc((size_t)2 * G4 * H_ * 2);
  unsigned short* wih1b = (unsigned short*)alloc((size_t)2 * G4 * 1024 * 2);
  unsigned short* whh1b = (unsigned short*)alloc((size_t)2 * G4 * H_ * 2);
  unsigned short* fcwb  = (unsigned short*)alloc((size_t)V_ * 1024 * 2);
  unsigned short* Xb    = (unsigned short*)alloc((size_t)SB * E_ * 2);
  unsigned short* H0    = (unsigned short*)alloc((size_t)SB * 1024 * 2);
  unsigned short* O1    = (unsigned short*)alloc((size_t)SB * 1024 * 2);
  unsigned short* h0i   = (unsigned short*)alloc((size_t)2 * B_ * H_ * 2);
  unsigned short* h1i   = (unsigned short*)alloc((size_t)2 * B_ * H_ * 2);
  float* b0s = (float*)alloc((size_t)2 * G4 * 4);
  float* b1s = (float*)alloc((size_t)2 * G4 * 4);
  unsigned* cnt0 = (unsigned*)alloc(CNT_BYTES);
  unsigned* cnt1 = (unsigned*)alloc(CNT_BYTES);
  (void)ws_size;

  // G0 lives in d_out (fully consumed before final GEMM overwrites it).
  float* G0 = (float*)d_out;   // (SB, NG) = 64 MB

  // --- prep ---
  k_f2bf<<<2048, 256, 0, stream>>>(wih0, wih0b, 2 * G4 * E_);
  k_f2bf<<<2048, 256, 0, stream>>>(whh0, whh0b, 2 * G4 * H_);
  k_f2bf<<<2048, 256, 0, stream>>>(wih1, wih1b, 2 * G4 * 1024);
  k_f2bf<<<2048, 256, 0, stream>>>(whh1, whh1b, 2 * G4 * H_);
  k_f2bf<<<4096, 256, 0, stream>>>(fcw, fcwb, V_ * 1024);
  k_addbias<<<16, 256, 0, stream>>>(bih0, bhh0, b0s, 2 * G4);
  k_addbias<<<16, 256, 0, stream>>>(bih1, bhh1, b1s, 2 * G4);
  k_gather<<<SB, 256, 0, stream>>>(Y, emb, Xb);
  k_init_h<<<512, 256, 0, stream>>>(hidden, h0i, h1i);
  (void)hipMemsetAsync(cnt0, 0, CNT_BYTES, stream);
  (void)hipMemsetAsync(cnt1, 0, CNT_BYTES, stream);

  // --- layer-0 input gates: G0 = X @ [wih0 both dirs]^T + b0 ---
  k_gemm_nt<false, false><<<(SB / 128) * (NG / 128), 256, 0, stream>>>(
      Xb, wih0b, b0s, G0, SB, NG, E_, NG / 128);

  // --- fused persistent recurrence (self-timed chains) ---
  k_fused_lstm<<<NBLK, 256, 0, stream>>>(h0i, h1i, cell, whh0b, wih1b, whh1b,
                                         b1s, G0, H0, O1, cnt0, cnt1);

  // --- final projection: out[b*64+t, v] = O1[t*64+b,:] @ fcw[v,:]^T + fcb[v] ---
  k_gemm_nt<true, true><<<(SB / 128) * (V_ / 128), 256, 0, stream>>>(
      O1, fcwb, fcb, (float*)d_out, SB, V_, 1024, V_ / 128);
}

// Round 8
// 1204.581 us; speedup vs baseline: 1.1830x; 1.0249x over previous
//
#include <hip/hip_runtime.h>
#include <hip/hip_bf16.h>
#include <stdint.h>

#define S_ 64
#define B_ 64
#define E_ 512
#define H_ 512
#define V_ 32000
#define G4 2048   // 4*H
#define SB 4096   // S*B
#define NG 4096   // G0 row width: 2 dirs * 4H

typedef __attribute__((ext_vector_type(8))) short short8;
typedef __attribute__((ext_vector_type(4))) float f32x4;
typedef __attribute__((ext_vector_type(4))) int i32x4;

static __device__ __forceinline__ unsigned short f2bf(float f) {
  unsigned u = __float_as_uint(f);
  u += 0x7fff + ((u >> 16) & 1);   // RNE
  return (unsigned short)(u >> 16);
}
static __device__ __forceinline__ float sigm(float x) {
  return 1.f / (1.f + expf(-x));
}

__device__ __forceinline__ void gload_lds16(const void* g, void* l) {
  __builtin_amdgcn_global_load_lds(
      (const __attribute__((address_space(1))) void*)g,
      (__attribute__((address_space(3))) void*)l, 16, 0, 0);
}

// coherent (device-visible) 16-byte store: write-through past the XCD L2
__device__ __forceinline__ void st128_sys(void* p, i32x4 v) {
  asm volatile("global_store_dwordx4 %0, %1, off sc0 sc1"
               :: "v"((unsigned long long)p), "v"(v) : "memory");
}
__device__ __forceinline__ void wait_vm0() {
  asm volatile("s_waitcnt vmcnt(0)" ::: "memory");
}

// relaxed spin until *c >= tgt (agent-scope atomic load bypasses XCD L2)
__device__ __forceinline__ void spin_ge(unsigned* c, unsigned tgt) {
  while (__hip_atomic_load(c, __ATOMIC_RELAXED, __HIP_MEMORY_SCOPE_AGENT) < tgt)
    __builtin_amdgcn_s_sleep(1);
}
__device__ __forceinline__ void arrive(unsigned* c) {
  __hip_atomic_fetch_add(c, 1u, __ATOMIC_RELAXED, __HIP_MEMORY_SCOPE_AGENT);
}

// counter slot index: per (step, dir, part), 256B apart
#define CIDX(t, d, p) ((((t) * 8) + ((d) * 4) + (p)) * 64)
#define CNT_BYTES (64 * 8 * 64 * 4)

__global__ void k_f2bf(const float* __restrict__ in, unsigned short* __restrict__ out, int n) {
  int i = blockIdx.x * blockDim.x + threadIdx.x;
  int stride = gridDim.x * blockDim.x;
  for (; i < n; i += stride) out[i] = f2bf(in[i]);
}

__global__ void k_addbias(const float* __restrict__ a, const float* __restrict__ b,
                          float* __restrict__ out, int n) {
  int i = blockIdx.x * blockDim.x + threadIdx.x;
  if (i < n) out[i] = a[i] + b[i];
}

__global__ void k_gather(const int* __restrict__ Y, const float* __restrict__ emb,
                         unsigned short* __restrict__ X) {
  int sb = blockIdx.x;
  int t = sb >> 6, b = sb & 63;
  int idx = (t == 0) ? Y[b * S_ + 1] : Y[b * S_ + t - 1];
  const float* src = emb + (size_t)idx * E_;
  unsigned short* dst = X + (size_t)sb * E_;
  for (int e = threadIdx.x; e < E_; e += blockDim.x) dst[e] = f2bf(src[e]);
}

__global__ void k_init_h(const float* __restrict__ hid,
                         unsigned short* __restrict__ h0i, unsigned short* __restrict__ h1i) {
  int i = blockIdx.x * blockDim.x + threadIdx.x;
  if (i >= 4 * B_ * H_) return;
  unsigned short v = f2bf(hid[i]);
  if (i < 2 * B_ * H_) h0i[i] = v;
  else h1i[i - 2 * B_ * H_] = v;
}

// ---------------- GEMM: C[M,N] = A[M,K] @ B[N,K]^T + bias (m97-style) ----------------
// bm-MAJOR block order (consecutive wgs share one B panel, sweep A) + bijective
// XCD swizzle (nwg % 8 == 0): live B working set ~2 MB instead of N/128 panels.
template <bool PERMUTE, bool NT>
__global__ __launch_bounds__(256) void k_gemm_nt(
    const unsigned short* __restrict__ A, const unsigned short* __restrict__ B,
    const float* __restrict__ bias, float* __restrict__ C,
    int M, int N, int K, int nTM, int nwg) {
  __shared__ unsigned short Als[128 * 32];
  __shared__ unsigned short Bls[128 * 32];
  int tid = threadIdx.x;
  int o = blockIdx.x;
  int wg = (o & 7) * (nwg >> 3) + (o >> 3);   // bijective XCD swizzle
  int bm = wg % nTM, bn = wg / nTM;           // bm-major
  int w = tid >> 6, l = tid & 63;
  int wr = w >> 1, wc = w & 1;
  int lr = l & 15, hi = l >> 4;
  int c0 = w * 128 + l;
  int row0 = c0 >> 2, ks0 = (((c0 & 3) ^ (row0 & 3)) * 8);
  int c1 = c0 + 64;
  int row1 = c1 >> 2, ks1 = (((c1 & 3) ^ (row1 & 3)) * 8);
  const unsigned short* Ab = A + (size_t)(bm * 128) * K;
  const unsigned short* Bb = B + (size_t)(bn * 128) * K;
  unsigned short* AlsW = &Als[w * 1024];
  unsigned short* BlsW = &Bls[w * 1024];
  int co = ((hi ^ (lr & 3)) * 8);
  f32x4 acc[4][4] = {};
  for (int kk = 0; kk < K; kk += 32) {
    __syncthreads();
    gload_lds16(Ab + (size_t)row0 * K + kk + ks0, AlsW);
    gload_lds16(Ab + (size_t)row1 * K + kk + ks1, AlsW + 512);
    gload_lds16(Bb + (size_t)row0 * K + kk + ks0, BlsW);
    gload_lds16(Bb + (size_t)row1 * K + kk + ks1, BlsW + 512);
    __syncthreads();
    short8 af[4], bfr[4];
#pragma unroll
    for (int r = 0; r < 4; r++)
      af[r] = *(const short8*)&Als[(wr * 64 + r * 16 + lr) * 32 + co];
#pragma unroll
    for (int c4 = 0; c4 < 4; c4++)
      bfr[c4] = *(const short8*)&Bls[(wc * 64 + c4 * 16 + lr) * 32 + co];
#pragma unroll
    for (int r = 0; r < 4; r++)
#pragma unroll
      for (int c4 = 0; c4 < 4; c4++)
        acc[r][c4] = __builtin_amdgcn_mfma_f32_16x16x32_bf16(af[r], bfr[c4], acc[r][c4], 0, 0, 0);
  }
  int rbase = bm * 128 + wr * 64 + hi * 4;
  int cbase = bn * 128 + wc * 64 + lr;
#pragma unroll
  for (int r = 0; r < 4; r++) {
#pragma unroll
    for (int c4 = 0; c4 < 4; c4++) {
      int cc = cbase + c4 * 16;
      float bv = bias[cc];
#pragma unroll
      for (int j = 0; j < 4; j++) {
        int rr = rbase + r * 16 + j;
        size_t orow = PERMUTE ? (size_t)((rr & 63) * 64 + (rr >> 6)) : (size_t)rr;
        float v = acc[r][c4][j] + bv;
        float* p = &C[orow * (size_t)N + cc];
        if (NT) __builtin_nontemporal_store(v, p);
        else *p = v;
      }
    }
  }
}

// ---------------- fused persistent 2-layer bidirectional LSTM (self-timed) ----------------
// 192 blocks: [0,64): layer 0 (d=blk>>5, jt=blk&31); [64,192): layer 1
// (idx=blk-64, d=idx>>6, jt8=idx&63). Producer/consumer flags:
//   cnt0[t][d][p] (tgt 8): H0[t] dir-d part-p published     (p = jt&3)
//   cnt1[t][d][p] (tgt 16): O1[t] dir-d part-p published    (p = jt8&3)
// l1 is software-pipelined: the x1@wih1 phase for step t+1 (depends only on
// H0[t+1], produced by l0 running ahead) is computed at the TAIL of step t,
// after publishing O1[t]. The recurrent chain is only {wait own flag ->
// fetch hprev (64KB) -> 16 MFMAs -> gates -> publish}.
#define LDW0 520    // l0: 64 rows x (512+8)
#define LDW1 1544   // l1: 32 rows x (1536+8)
#define NBLK 192

__global__ __launch_bounds__(256) void k_fused_lstm(
    const unsigned short* __restrict__ h0i,   // (2,B,H) bf16
    const unsigned short* __restrict__ h1i,   // (2,B,H) bf16
    const float* __restrict__ cell,           // (4,B,H) fp32 [l0f,l0b,l1f,l1b]
    const unsigned short* __restrict__ whh0,  // (2,2048,512) bf16
    const unsigned short* __restrict__ wih1,  // (2,2048,1024) bf16
    const unsigned short* __restrict__ whh1,  // (2,2048,512) bf16
    const float* __restrict__ b1s,            // (2,2048) fp32
    const float* __restrict__ G0,             // (SB,NG) fp32
    unsigned short* __restrict__ H0,          // (SB,1024) bf16  layer-0 output
    unsigned short* __restrict__ O1,          // (SB,1024) bf16  layer-1 output
    unsigned* __restrict__ cnt0, unsigned* __restrict__ cnt1) {
  __shared__ unsigned short SM[32 * LDW1];    // 98,816 B (l0 uses 66,560 of it)
  __shared__ __align__(16) unsigned short HS[64 * 16];  // publish staging
  int tid = threadIdx.x;
  int w = tid >> 6, l = tid & 63;
  int lr = l & 15, hi = l >> 4;

  if (blockIdx.x < 64) {
    // ================= LAYER 0 =================
    int d = blockIdx.x >> 5, jt = blockIdx.x & 31;
    const unsigned short* Wd = whh0 + (size_t)d * (G4 * H_);
    for (int c = tid; c < 64 * 64; c += 256) {
      int row = c >> 6, ck = c & 63;
      int g = row >> 4, r16 = row & 15;
      *(int4*)&SM[row * LDW0 + ck * 8] =
          *(const int4*)&Wd[(size_t)(g * H_ + jt * 16 + r16) * H_ + ck * 8];
    }
    int j = jt * 16 + lr;
    int b0 = w * 16 + hi * 4;
    f32x4 creg;
    {
      const float* cd = cell + (size_t)d * (B_ * H_);
#pragma unroll
      for (int jj = 0; jj < 4; jj++) creg[jj] = cd[(size_t)(b0 + jj) * H_ + j];
    }
    __syncthreads();
    const float* G_dj = G0 + d * G4;
    float gv[4][4];
    auto preloadG = [&](int t) {
#pragma unroll
      for (int jj = 0; jj < 4; jj++) {
        const float* Gb = G_dj + (size_t)(t * B_ + b0 + jj) * NG;
#pragma unroll
        for (int g = 0; g < 4; g++) gv[g][jj] = Gb[g * 512 + j];
      }
    };
    preloadG(0);
    for (int t = 0; t < S_; ++t) {
      if (t >= 1) {
        if (tid < 4) spin_ge(&cnt0[CIDX(t - 1, d, tid)], 8);
        __syncthreads();
      }
      const unsigned short* hp = (t == 0) ? h0i + (size_t)d * (B_ * H_)
                                          : H0 + (size_t)(t - 1) * B_ * 1024 + d * 512;
      size_t hstr = (t == 0) ? (size_t)H_ : 1024;
      const unsigned short* arow = hp + (size_t)(w * 16 + lr) * hstr + hi * 8;
      f32x4 acc[4] = {};
#pragma unroll
      for (int ki = 0; ki < 16; ki++) {
        short8 a = *(const short8*)&arow[ki * 32];
#pragma unroll
        for (int g = 0; g < 4; g++) {
          short8 bfr = *(const short8*)&SM[(g * 16 + lr) * LDW0 + ki * 32 + hi * 8];
          acc[g] = __builtin_amdgcn_mfma_f32_16x16x32_bf16(a, bfr, acc[g], 0, 0, 0);
        }
      }
#pragma unroll
      for (int jj = 0; jj < 4; jj++) {
        float gi = acc[0][jj] + gv[0][jj];
        float gf = acc[1][jj] + gv[1][jj];
        float gg = acc[2][jj] + gv[2][jj];
        float go = acc[3][jj] + gv[3][jj];
        float c = sigm(gf) * creg[jj] + sigm(gi) * tanhf(gg);
        creg[jj] = c;
        HS[(b0 + jj) * 16 + lr] = f2bf(sigm(go) * tanhf(c));
      }
      __syncthreads();
      unsigned short* Ho = H0 + (size_t)t * B_ * 1024 + d * 512 + jt * 16;
      if (tid < 128) {
        int r = tid >> 1, half = tid & 1;
        i32x4 v = *(const i32x4*)&HS[r * 16 + half * 8];
        st128_sys(&Ho[(size_t)r * 1024 + half * 8], v);
      }
      wait_vm0();
      __syncthreads();
      if (tid == 0) arrive(&cnt0[CIDX(t, d, jt & 3)]);
      if (t + 1 < S_) preloadG(t + 1);
    }
  } else {
    // ================= LAYER 1 (pipelined) =================
    int idx = blockIdx.x - 64;
    int d = idx >> 6, jt8 = idx & 63;
    int j0 = jt8 * 8;
    {
      const unsigned short* Wih = wih1 + (size_t)d * (G4 * 1024);
      const unsigned short* Whh = whh1 + (size_t)d * (G4 * H_);
      for (int c = tid; c < 32 * 192; c += 256) {
        int r = c / 192, ck = c - r * 192;
        int g = r >> 3, jc = r & 7;
        const unsigned short* src =
            (ck < 128) ? Wih + (size_t)(g * H_ + j0 + jc) * 1024 + ck * 8
                       : Whh + (size_t)(g * H_ + j0 + jc) * H_ + (ck - 128) * 8;
        *(int4*)&SM[r * LDW1 + ck * 8] = *(const int4*)src;
      }
    }
    int j = j0 + (lr & 7);
    const float* b1d = b1s + d * G4;
    float bi_ = b1d[j], bf_ = b1d[512 + j], bg_ = b1d[1024 + j], bo_ = b1d[1536 + j];
    int b0 = w * 16 + hi * 4;
    f32x4 creg = {};
    if (lr < 8) {
      const float* cd = cell + (size_t)(2 + d) * (B_ * H_);
#pragma unroll
      for (int jj = 0; jj < 4; jj++) creg[jj] = cd[(size_t)(b0 + jj) * H_ + j];
    }
    __syncthreads();

    f32x4 acc0, acc1;   // carry wih-part across the iteration boundary
    // prologue: x1 phase for t=0
    {
      if (tid < 8) spin_ge(&cnt0[CIDX(0, 0, 0) + tid * 64], 8);
      __syncthreads();
      acc0 = {}; acc1 = {};
      const unsigned short* x1row = H0 + ((size_t)0 * B_ + w * 16 + lr) * 1024 + hi * 8;
#pragma unroll 8
      for (int ki = 0; ki < 32; ki++) {
        short8 a = *(const short8*)&x1row[ki * 32];
        short8 bA = *(const short8*)&SM[(size_t)lr * LDW1 + ki * 32 + hi * 8];
        short8 bB = *(const short8*)&SM[(size_t)(16 + lr) * LDW1 + ki * 32 + hi * 8];
        acc0 = __builtin_amdgcn_mfma_f32_16x16x32_bf16(a, bA, acc0, 0, 0, 0);
        acc1 = __builtin_amdgcn_mfma_f32_16x16x32_bf16(a, bB, acc1, 0, 0, 0);
      }
    }
    for (int t = 0; t < S_; ++t) {
      // recurrent phase: wait own-dir O1[t-1], add hprev @ whh1
      if (t >= 1) {
        if (tid < 4) spin_ge(&cnt1[CIDX(t - 1, d, tid)], 16);
        __syncthreads();
      }
      const unsigned short* hprev = (t == 0)
          ? h1i + (size_t)d * (B_ * H_) + (size_t)(w * 16 + lr) * H_ + hi * 8
          : O1 + ((size_t)(t - 1) * B_ + w * 16 + lr) * 1024 + d * 512 + hi * 8;
#pragma unroll 8
      for (int ki = 0; ki < 16; ki++) {
        short8 a = *(const short8*)&hprev[ki * 32];
        short8 bA = *(const short8*)&SM[(size_t)lr * LDW1 + 1024 + ki * 32 + hi * 8];
        short8 bB = *(const short8*)&SM[(size_t)(16 + lr) * LDW1 + 1024 + ki * 32 + hi * 8];
        acc0 = __builtin_amdgcn_mfma_f32_16x16x32_bf16(a, bA, acc0, 0, 0, 0);
        acc1 = __builtin_amdgcn_mfma_f32_16x16x32_bf16(a, bB, acc1, 0, 0, 0);
      }
      float pf[4], po[4];
#pragma unroll
      for (int jj = 0; jj < 4; jj++) {
        pf[jj] = __shfl_xor(acc0[jj], 8);
        po[jj] = __shfl_xor(acc1[jj], 8);
      }
      if (lr < 8) {
#pragma unroll
        for (int jj = 0; jj < 4; jj++) {
          float gi = acc0[jj] + bi_;
          float gf = pf[jj] + bf_;
          float gg = acc1[jj] + bg_;
          float go = po[jj] + bo_;
          float c = sigm(gf) * creg[jj] + sigm(gi) * tanhf(gg);
          creg[jj] = c;
          HS[(b0 + jj) * 8 + lr] = f2bf(sigm(go) * tanhf(c));
        }
      }
      __syncthreads();
      unsigned short* Oo = O1 + (size_t)t * B_ * 1024 + d * 512 + j0;
      if (tid < 64) {
        i32x4 v = *(const i32x4*)&HS[tid * 8];
        st128_sys(&Oo[(size_t)tid * 1024], v);
      }
      wait_vm0();
      __syncthreads();
      if (tid == 0 && t + 1 < S_) arrive(&cnt1[CIDX(t, d, jt8 & 3)]);
      // tail: x1 phase for t+1 (overlaps peers' publish + flag propagation)
      if (t + 1 < S_) {
        if (tid < 8) spin_ge(&cnt0[CIDX(t + 1, 0, 0) + tid * 64], 8);
        __syncthreads();
        acc0 = {}; acc1 = {};
        const unsigned short* x1row =
            H0 + ((size_t)(t + 1) * B_ + w * 16 + lr) * 1024 + hi * 8;
#pragma unroll 8
        for (int ki = 0; ki < 32; ki++) {
          short8 a = *(const short8*)&x1row[ki * 32];
          short8 bA = *(const short8*)&SM[(size_t)lr * LDW1 + ki * 32 + hi * 8];
          short8 bB = *(const short8*)&SM[(size_t)(16 + lr) * LDW1 + ki * 32 + hi * 8];
          acc0 = __builtin_amdgcn_mfma_f32_16x16x32_bf16(a, bA, acc0, 0, 0, 0);
          acc1 = __builtin_amdgcn_mfma_f32_16x16x32_bf16(a, bB, acc1, 0, 0, 0);
        }
      }
    }
  }
}

extern "C" void kernel_launch(void* const* d_in, const int* in_sizes, int n_in,
                              void* d_out, int out_size, void* d_ws, size_t ws_size,
                              hipStream_t stream) {
  const float* hidden = (const float*)d_in[0];
  const float* cell   = (const float*)d_in[1];
  const int*   Y      = (const int*)d_in[2];
  const float* emb    = (const float*)d_in[3];
  const float* wih0   = (const float*)d_in[4];
  const float* whh0   = (const float*)d_in[5];
  const float* bih0   = (const float*)d_in[6];
  const float* bhh0   = (const float*)d_in[7];
  const float* wih1   = (const float*)d_in[8];
  const float* whh1   = (const float*)d_in[9];
  const float* bih1   = (const float*)d_in[10];
  const float* bhh1   = (const float*)d_in[11];
  const float* fcw    = (const float*)d_in[12];
  const float* fcb    = (const float*)d_in[13];

  char* ws = (char*)d_ws;
  size_t off = 0;
  auto alloc = [&](size_t bytes) {
    void* p = ws + off;
    off += (bytes + 255) & ~(size_t)255;
    return p;
  };
  unsigned short* wih0b = (unsigned short*)alloc((size_t)2 * G4 * E_ * 2);
  unsigned short* whh0b = (unsigned short*)alloc((size_t)2 * G4 * H_ * 2);
  unsigned short* wih1b = (unsigned short*)alloc((size_t)2 * G4 * 1024 * 2);
  unsigned short* whh1b = (unsigned short*)alloc((size_t)2 * G4 * H_ * 2);
  unsigned short* fcwb  = (unsigned short*)alloc((size_t)V_ * 1024 * 2);
  unsigned short* Xb    = (unsigned short*)alloc((size_t)SB * E_ * 2);
  unsigned short* H0    = (unsigned short*)alloc((size_t)SB * 1024 * 2);
  unsigned short* O1    = (unsigned short*)alloc((size_t)SB * 1024 * 2);
  unsigned short* h0i   = (unsigned short*)alloc((size_t)2 * B_ * H_ * 2);
  unsigned short* h1i   = (unsigned short*)alloc((size_t)2 * B_ * H_ * 2);
  float* b0s = (float*)alloc((size_t)2 * G4 * 4);
  float* b1s = (float*)alloc((size_t)2 * G4 * 4);
  unsigned* cnt0 = (unsigned*)alloc(CNT_BYTES);
  unsigned* cnt1 = (unsigned*)alloc(CNT_BYTES);
  (void)ws_size;

  // G0 lives in d_out (fully consumed before final GEMM overwrites it).
  float* G0 = (float*)d_out;   // (SB, NG) = 64 MB

  // --- prep ---
  k_f2bf<<<2048, 256, 0, stream>>>(wih0, wih0b, 2 * G4 * E_);
  k_f2bf<<<2048, 256, 0, stream>>>(whh0, whh0b, 2 * G4 * H_);
  k_f2bf<<<2048, 256, 0, stream>>>(wih1, wih1b, 2 * G4 * 1024);
  k_f2bf<<<2048, 256, 0, stream>>>(whh1, whh1b, 2 * G4 * H_);
  k_f2bf<<<4096, 256, 0, stream>>>(fcw, fcwb, V_ * 1024);
  k_addbias<<<16, 256, 0, stream>>>(bih0, bhh0, b0s, 2 * G4);
  k_addbias<<<16, 256, 0, stream>>>(bih1, bhh1, b1s, 2 * G4);
  k_gather<<<SB, 256, 0, stream>>>(Y, emb, Xb);
  k_init_h<<<512, 256, 0, stream>>>(hidden, h0i, h1i);
  (void)hipMemsetAsync(cnt0, 0, CNT_BYTES, stream);
  (void)hipMemsetAsync(cnt1, 0, CNT_BYTES, stream);

  // --- layer-0 input gates: G0 = X @ [wih0 both dirs]^T + b0 ---
  k_gemm_nt<false, false><<<(SB / 128) * (NG / 128), 256, 0, stream>>>(
      Xb, wih0b, b0s, G0, SB, NG, E_, SB / 128, (SB / 128) * (NG / 128));

  // --- fused persistent recurrence (self-timed chains, l1 pipelined) ---
  k_fused_lstm<<<NBLK, 256, 0, stream>>>(h0i, h1i, cell, whh0b, wih1b, whh1b,
                                         b1s, G0, H0, O1, cnt0, cnt1);

  // --- final projection: out[b*64+t, v] = O1[t*64+b,:] @ fcw[v,:]^T + fcb[v] ---
  k_gemm_nt<true, true><<<(SB / 128) * (V_ / 128), 256, 0, stream>>>(
      O1, fcwb, fcb, (float*)d_out, SB, V_, 1024, SB / 128, (SB / 128) * (V_ / 128));
}